// Round 8
// baseline (519.617 us; speedup 1.0000x reference)
//
#include <hip/hip_runtime.h>

#define N_NODES 50000
#define NPAD 50176            // 392 * 128
#define N_EDGES 800000
#define EPS_C 1e-5f
#define SLOPE_C 0.01f

typedef __attribute__((ext_vector_type(8))) short short8v;
typedef __attribute__((ext_vector_type(4))) float f32x4;

// ---------- bf16 helpers (RNE) ----------
__device__ __forceinline__ unsigned short f2bf(float f) {
  unsigned u = __float_as_uint(f);
  u += 0x7fffu + ((u >> 16) & 1u);
  return (unsigned short)(u >> 16);
}
__device__ __forceinline__ unsigned packbf(float a, float b) {
  return (unsigned)f2bf(a) | ((unsigned)f2bf(b) << 16);
}
__device__ __forceinline__ float bflo(unsigned u) { return __uint_as_float(u << 16); }
__device__ __forceinline__ float bfhi(unsigned u) { return __uint_as_float(u & 0xffff0000u); }

// ---------- async global->LDS, 16 B per lane ----------
__device__ __forceinline__ void gload16(const unsigned short* g, unsigned short* l) {
  __builtin_amdgcn_global_load_lds(
      (const __attribute__((address_space(1))) unsigned int*)g,
      (__attribute__((address_space(3))) unsigned int*)l, 16, 0, 0);
}

// ---------------- all-weights transpose + cast: Wt[m][k] = bf16(W[k][m]) ----------------
__global__ void wcast_all_kernel(const float* __restrict__ W1, const float* __restrict__ W2,
                                 const float* __restrict__ W3, const float* __restrict__ W4,
                                 unsigned short* __restrict__ Wt1, unsigned short* __restrict__ Wt2,
                                 unsigned short* __restrict__ Wt3, unsigned short* __restrict__ Wt4) {
  const int y = blockIdx.y;
  const int idx = blockIdx.x * 256 + threadIdx.x;
  const float* W;
  unsigned short* Wt;
  int K, mshift, mmask, total;
  switch (y) {
    case 0: W = W1; Wt = Wt1; K = 128; mshift = 8; mmask = 255; total = 32768; break;
    case 1: W = W2; Wt = Wt2; K = 256; mshift = 8; mmask = 255; total = 65536; break;
    case 2: W = W3; Wt = Wt3; K = 256; mshift = 8; mmask = 255; total = 65536; break;
    default: W = W4; Wt = Wt4; K = 256; mshift = 7; mmask = 127; total = 32768; break;
  }
  if (idx >= total) return;
  const int k = idx >> mshift;
  const int m = idx & mmask;
  Wt[(size_t)m * K + k] = f2bf(W[idx]);
}

// ---------------- MFMA GEMM v3: 2-phase double-buffered A+B via global_load_lds ----------------
// A: NPAD x KC bf16 (pad rows zero). Wt: M x KC bf16.
// MODE 0: Yb = bf16(A·Wt^T)          MODE 1: Yb = bf16(A·Wt^T + bias) + fused col stats
template <int MODE, int KC>
__global__ __launch_bounds__(256) void gemm3_kernel(
    const unsigned short* __restrict__ A, const unsigned short* __restrict__ Wt,
    const float* __restrict__ bias, unsigned short* __restrict__ Yb,
    float* __restrict__ colsum, float* __restrict__ colsumsq, int M) {
  __shared__ __align__(16) unsigned short As[2][128][64];  // src-swizzled, linear dest
  __shared__ __align__(16) unsigned short Bs[2][64][64];
  __shared__ float sred[2][64][2];
  const int tid = threadIdx.x;
  const int lane = tid & 63;
  const int wave = tid >> 6;
  const int wr = wave >> 1, wc = wave & 1;
  const int row0 = blockIdx.x * 128;
  const int col0 = blockIdx.y * 64;
  const int l15 = lane & 15;
  const int lhi = lane >> 4;

  auto stage = [&](int b, int k0) {
    // A tile 128x64: 1024 16B chunks, LDS linear, global src pre-swizzled
#pragma unroll
    for (int c = 0; c < 4; ++c) {
      const int chunk = (c * 4 + wave) * 64 + lane;
      const int r = chunk >> 3;
      const int ck = (chunk & 7) ^ (r & 7);
      gload16(&A[(size_t)(row0 + r) * KC + k0 + ck * 8], &As[b][0][0] + chunk * 8);
    }
    // B tile 64x64: 512 16B chunks
#pragma unroll
    for (int c = 0; c < 2; ++c) {
      const int chunk = (c * 4 + wave) * 64 + lane;
      const int rb = chunk >> 3;
      const int cb = (chunk & 7) ^ (rb & 7);
      gload16(&Wt[(size_t)(col0 + rb) * KC + k0 + cb * 8], &Bs[b][0][0] + chunk * 8);
    }
  };

  f32x4 acc[4][2];
#pragma unroll
  for (int i = 0; i < 4; ++i)
#pragma unroll
    for (int j = 0; j < 2; ++j) acc[i][j] = (f32x4){0.f, 0.f, 0.f, 0.f};

  constexpr int NK = KC / 64;
  stage(0, 0);
  __syncthreads();  // drain: buf0 resident
#pragma unroll
  for (int step = 0; step < NK; ++step) {
    if (step + 1 < NK) stage((step + 1) & 1, (step + 1) * 64);  // prefetch next, other buffer
    const int b = step & 1;
    short8v bfr[2][2];
#pragma unroll
    for (int nr = 0; nr < 2; ++nr)
#pragma unroll
      for (int h = 0; h < 2; ++h) {
        const int rowb = wc * 32 + nr * 16 + l15;
        const int chb = (h * 4 + lhi) ^ (rowb & 7);
        bfr[nr][h] = *reinterpret_cast<const short8v*>(&Bs[b][rowb][chb * 8]);
      }
#pragma unroll
    for (int mr = 0; mr < 4; ++mr) {
#pragma unroll
      for (int h = 0; h < 2; ++h) {
        const int rowa = wr * 64 + mr * 16 + l15;
        const int cha = (h * 4 + lhi) ^ (rowa & 7);
        const short8v af = *reinterpret_cast<const short8v*>(&As[b][rowa][cha * 8]);
#pragma unroll
        for (int nr = 0; nr < 2; ++nr)
          acc[mr][nr] = __builtin_amdgcn_mfma_f32_16x16x32_bf16(
              af, bfr[nr][h], acc[mr][nr], 0, 0, 0);
      }
    }
    __syncthreads();  // next buffer resident; readers of b done before it is overwritten
  }
  // ---- epilogue: unguarded stores (pads zero+harmless); stats guarded to real rows ----
  float bcol[2] = {0.f, 0.f};
  if constexpr (MODE == 1) {
#pragma unroll
    for (int nr = 0; nr < 2; ++nr) bcol[nr] = bias[col0 + wc * 32 + nr * 16 + l15];
  }
  float s_c[2] = {0.f, 0.f}, q_c[2] = {0.f, 0.f};
#pragma unroll
  for (int mr = 0; mr < 4; ++mr) {
#pragma unroll
    for (int r = 0; r < 4; ++r) {
      const int grow = row0 + wr * 64 + mr * 16 + lhi * 4 + r;
#pragma unroll
      for (int nr = 0; nr < 2; ++nr) {
        const int gcol = col0 + wc * 32 + nr * 16 + l15;
        const float v = acc[mr][nr][r] + bcol[nr];
        Yb[(size_t)grow * M + gcol] = f2bf(v);
        if constexpr (MODE == 1) {
          if (grow < N_NODES) {
            s_c[nr] += v;
            q_c[nr] += v * v;
          }
        }
      }
    }
  }
  if constexpr (MODE == 1) {
#pragma unroll
    for (int nr = 0; nr < 2; ++nr) {
      float s = s_c[nr], q = q_c[nr];
      s += __shfl_xor(s, 16, 64); q += __shfl_xor(q, 16, 64);
      s += __shfl_xor(s, 32, 64); q += __shfl_xor(q, 32, 64);
      if (lhi == 0) {
        const int cl = wc * 32 + nr * 16 + l15;
        sred[0][cl][wr] = s;
        sred[1][cl][wr] = q;
      }
    }
    __syncthreads();
    if (tid < 128) {
      const int which = tid >> 6;
      const int cl = tid & 63;
      const float tot = sred[which][cl][0] + sred[which][cl][1];
      float* dstp = which ? colsumsq : colsum;
      atomicAdd(&dstp[col0 + cl], tot);
    }
  }
}

// ---------------- degree histogram ----------------
__global__ void hist_kernel(const int* __restrict__ dst, int* __restrict__ hist, int E) {
  const int e = blockIdx.x * 256 + threadIdx.x;
  if (e < E) atomicAdd(&hist[dst[e]], 1);
}

// ---------------- two-level exclusive scan (scan1 also emits nisq) ----------------
__global__ __launch_bounds__(1024) void scan1_kernel(
    const int* __restrict__ hist, int* __restrict__ off, int* __restrict__ partial,
    float* __restrict__ nisq, int n) {
  __shared__ int tmp[1024];
  const int tid = threadIdx.x;
  const int i = blockIdx.x * 1024 + tid;
  const int v = (i < n) ? hist[i] : 0;
  tmp[tid] = v;
  __syncthreads();
  int x = v;
  for (int o = 1; o < 1024; o <<= 1) {
    const int y = (tid >= o) ? tmp[tid - o] : 0;
    __syncthreads();
    x += y;
    tmp[tid] = x;
    __syncthreads();
  }
  if (i < n) {
    off[i] = x - v;
    nisq[i] = rsqrtf((float)v + 1.0f);
  }
  if (tid == 1023) partial[blockIdx.x] = x;
}

__global__ __launch_bounds__(64) void scan2_kernel(
    const int* __restrict__ partial, int* __restrict__ partialoff,
    int* __restrict__ offN, int nb) {
  const int tid = threadIdx.x;
  const int v = (tid < nb) ? partial[tid] : 0;
  int x = v;
  for (int o = 1; o < 64; o <<= 1) {
    const int y = __shfl_up(x, o, 64);
    if (tid >= o) x += y;
  }
  if (tid < nb) partialoff[tid] = x - v;
  if (tid == 63) *offN = x;
}

__global__ void scan3_kernel(int* __restrict__ off, int* __restrict__ cursor,
                             const int* __restrict__ partialoff, int n) {
  const int i = blockIdx.x * 256 + threadIdx.x;
  if (i < n) {
    const int o = off[i] + partialoff[i >> 10];
    off[i] = o;
    cursor[i] = o;
  }
}

// ---------------- scatter edges into dst-sorted order ----------------
__global__ void scatter_kernel(const int* __restrict__ src, const int* __restrict__ dst,
                               int* __restrict__ cursor, int* __restrict__ esorted, int E) {
  const int e = blockIdx.x * 256 + threadIdx.x;
  if (e < E) {
    const int p = atomicAdd(&cursor[dst[e]], 1);
    esorted[p] = src[e];
  }
}

// ---------------- scale+cast: xs = bf16(x * nisq[row]), DI=128 ----------------
__global__ void scale_cast_kernel(const float* __restrict__ x,
                                  const float* __restrict__ nisq,
                                  unsigned short* __restrict__ xs) {
  const int idx = blockIdx.x * 256 + threadIdx.x;
  if (idx >= N_NODES * 32) return;
  const int row = idx >> 5;
  const int c = (idx & 31) * 4;
  const float s = nisq[row];
  const float4 v = *reinterpret_cast<const float4*>(&x[(size_t)row * 128 + c]);
  ushort4 o;
  o.x = f2bf(v.x * s); o.y = f2bf(v.y * s);
  o.z = f2bf(v.z * s); o.w = f2bf(v.w * s);
  *reinterpret_cast<ushort4*>(&xs[(size_t)row * 128 + c]) = o;
}

// ---------------- pure gather aggregation (half-wave, 16B/lane); zeroes pad rows ----------------
template <int DO, bool ADD_BIAS, bool HAS_RES, bool OUT_BF16>
__global__ __launch_bounds__(256) void aggregate4_kernel(
    const unsigned short* __restrict__ Y, const int* __restrict__ segoff,
    const int* __restrict__ esorted, const float* __restrict__ nisq,
    const float* __restrict__ bias, const float* __restrict__ resid,
    void* __restrict__ Tv) {
  constexpr int V2 = DO / 32;  // bf16 elems per lane per row (128: 4, 256: 8)
  const int wave = threadIdx.x >> 6;
  const int lane = threadIdx.x & 63;
  const int half = lane >> 5;
  const int l31 = lane & 31;
  const int n = blockIdx.x * 4 + wave;
  const int colbase = l31 * V2;
  if (n >= N_NODES) {  // pad row: write zeros so GEMM can load unguarded
    if (half == 0) {
      if constexpr (OUT_BF16) {
        unsigned short* tr = (unsigned short*)Tv + (size_t)n * DO + colbase;
        if constexpr (V2 == 8) *reinterpret_cast<uint4*>(tr) = (uint4){0, 0, 0, 0};
        else *reinterpret_cast<uint2*>(tr) = (uint2){0, 0};
      } else {
        float* tr = (float*)Tv + (size_t)n * DO + colbase;
        if constexpr (V2 == 8) {
          *reinterpret_cast<float4*>(tr) = (float4){0.f, 0.f, 0.f, 0.f};
          *reinterpret_cast<float4*>(tr + 4) = (float4){0.f, 0.f, 0.f, 0.f};
        } else {
          *reinterpret_cast<float4*>(tr) = (float4){0.f, 0.f, 0.f, 0.f};
        }
      }
    }
    return;
  }
  const unsigned short* Yc = Y + colbase;
  float a0[V2], a1[V2];
#pragma unroll
  for (int i = 0; i < V2; ++i) { a0[i] = 0.f; a1[i] = 0.f; }
  const int s = segoff[n];
  const int e = segoff[n + 1];

  if constexpr (V2 == 8) {
    auto acc8 = [&](float* a, const uint4 v) {
      a[0] += bflo(v.x); a[1] += bfhi(v.x);
      a[2] += bflo(v.y); a[3] += bfhi(v.y);
      a[4] += bflo(v.z); a[5] += bfhi(v.z);
      a[6] += bflo(v.w); a[7] += bfhi(v.w);
    };
    int j = s + half;
    for (; j + 2 < e; j += 4) {
      const int i0 = esorted[j];
      const int i1 = esorted[j + 2];
      const uint4 v0 = *reinterpret_cast<const uint4*>(Yc + (size_t)i0 * DO);
      const uint4 v1 = *reinterpret_cast<const uint4*>(Yc + (size_t)i1 * DO);
      acc8(a0, v0); acc8(a1, v1);
    }
    if (j < e) acc8(a0, *reinterpret_cast<const uint4*>(Yc + (size_t)esorted[j] * DO));
    if (half == 0) acc8(a1, *reinterpret_cast<const uint4*>(Yc + (size_t)n * DO));
  } else {
    auto acc4 = [&](float* a, const uint2 v) {
      a[0] += bflo(v.x); a[1] += bfhi(v.x);
      a[2] += bflo(v.y); a[3] += bfhi(v.y);
    };
    int j = s + half;
    for (; j + 2 < e; j += 4) {
      const int i0 = esorted[j];
      const int i1 = esorted[j + 2];
      const uint2 v0 = *reinterpret_cast<const uint2*>(Yc + (size_t)i0 * DO);
      const uint2 v1 = *reinterpret_cast<const uint2*>(Yc + (size_t)i1 * DO);
      acc4(a0, v0); acc4(a1, v1);
    }
    if (j < e) acc4(a0, *reinterpret_cast<const uint2*>(Yc + (size_t)esorted[j] * DO));
    if (half == 0) acc4(a1, *reinterpret_cast<const uint2*>(Yc + (size_t)n * DO));
  }

  const float sc = nisq[n];
  float vals[V2];
#pragma unroll
  for (int i = 0; i < V2; ++i) {
    float t = a0[i] + a1[i];
    t += __shfl_xor(t, 32, 64);
    t *= sc;
    if (half == 0) {
      if (ADD_BIAS) t += bias[colbase + i];
      if (HAS_RES) t += resid[(size_t)n * DO + colbase + i];
    }
    vals[i] = t;
  }
  if (half == 0) {
    if constexpr (OUT_BF16) {
      unsigned short* tr = (unsigned short*)Tv + (size_t)n * DO + colbase;
      if constexpr (V2 == 8) {
        uint4 o;
        o.x = packbf(vals[0], vals[1]); o.y = packbf(vals[2], vals[3]);
        o.z = packbf(vals[4], vals[5]); o.w = packbf(vals[6], vals[7]);
        *reinterpret_cast<uint4*>(tr) = o;
      } else {
        uint2 o;
        o.x = packbf(vals[0], vals[1]); o.y = packbf(vals[2], vals[3]);
        *reinterpret_cast<uint2*>(tr) = o;
      }
    } else {
      float* tr = (float*)Tv + (size_t)n * DO + colbase;
      if constexpr (V2 == 8) {
        float4 o0 = {vals[0], vals[1], vals[2], vals[3]};
        float4 o1 = {vals[4], vals[5], vals[6], vals[7]};
        *reinterpret_cast<float4*>(tr) = o0;
        *reinterpret_cast<float4*>(tr + 4) = o1;
      } else {
        float4 o = {vals[0], vals[1], vals[2], vals[3]};
        *reinterpret_cast<float4*>(tr) = o;
      }
    }
  }
}

// ---------------- column sums for BN stats (bf16 input, L4 only) ----------------
__global__ void stats_bf16_kernel(const unsigned short* __restrict__ T,
                                  float* __restrict__ colsum, float* __restrict__ colsumsq,
                                  int n, int rowsPerBlock) {
  const int t = threadIdx.x;   // 128 threads; thread handles 2 cols (one uint) over half rows
  const int c2 = t & 63;
  const int rh = t >> 6;
  const int r0 = blockIdx.x * rowsPerBlock;
  int r1 = r0 + rowsPerBlock;
  if (r1 > n) r1 = n;
  const unsigned* T32 = (const unsigned*)T;
  float s0 = 0.f, q0 = 0.f, s1 = 0.f, q1 = 0.f;
  for (int r = r0 + rh; r < r1; r += 2) {
    const unsigned v = T32[(size_t)r * 64 + c2];
    const float a = bflo(v), b = bfhi(v);
    s0 += a; q0 += a * a;
    s1 += b; q1 += b * b;
  }
  atomicAdd(&colsum[c2 * 2], s0);
  atomicAdd(&colsumsq[c2 * 2], q0);
  atomicAdd(&colsum[c2 * 2 + 1], s1);
  atomicAdd(&colsumsq[c2 * 2 + 1], q1);
}

// ---------------- BN apply + LeakyReLU + nisq row-scale, bf16 -> bf16 (DO=256); zero pads ----
__global__ void bn_lrelu_nisq_kernel(const unsigned short* __restrict__ Tb,
                                     const float* __restrict__ colsum,
                                     const float* __restrict__ colsumsq,
                                     const float* __restrict__ g, const float* __restrict__ be,
                                     const float* __restrict__ nisq,
                                     unsigned short* __restrict__ outb,
                                     size_t total8, float invN) {
  const size_t idx = (size_t)blockIdx.x * 256 + threadIdx.x;
  if (idx >= total8) return;
  const int row = (int)(idx >> 5);
  if (row >= N_NODES) {  // pad row: table must stay zero for next GEMM
    *reinterpret_cast<uint4*>(&outb[idx * 8]) = (uint4){0, 0, 0, 0};
    return;
  }
  const unsigned c = ((unsigned)idx & 31u) * 8;
  const float sc = nisq[row];
  uint4 v = *reinterpret_cast<const uint4*>(&Tb[idx * 8]);
  float z[8] = {bflo(v.x), bfhi(v.x), bflo(v.y), bfhi(v.y),
                bflo(v.z), bfhi(v.z), bflo(v.w), bfhi(v.w)};
  const float4 cs0 = *reinterpret_cast<const float4*>(&colsum[c]);
  const float4 cs1 = *reinterpret_cast<const float4*>(&colsum[c + 4]);
  const float4 cq0 = *reinterpret_cast<const float4*>(&colsumsq[c]);
  const float4 cq1 = *reinterpret_cast<const float4*>(&colsumsq[c + 4]);
  const float4 gv0 = *reinterpret_cast<const float4*>(&g[c]);
  const float4 gv1 = *reinterpret_cast<const float4*>(&g[c + 4]);
  const float4 bv0 = *reinterpret_cast<const float4*>(&be[c]);
  const float4 bv1 = *reinterpret_cast<const float4*>(&be[c + 4]);
  const float css[8] = {cs0.x, cs0.y, cs0.z, cs0.w, cs1.x, cs1.y, cs1.z, cs1.w};
  const float cqq[8] = {cq0.x, cq0.y, cq0.z, cq0.w, cq1.x, cq1.y, cq1.z, cq1.w};
  const float ggg[8] = {gv0.x, gv0.y, gv0.z, gv0.w, gv1.x, gv1.y, gv1.z, gv1.w};
  const float bbb[8] = {bv0.x, bv0.y, bv0.z, bv0.w, bv1.x, bv1.y, bv1.z, bv1.w};
#pragma unroll
  for (int k = 0; k < 8; ++k) {
    const float m = css[k] * invN;
    const float rs = rsqrtf(cqq[k] * invN - m * m + EPS_C);
    float zz = (z[k] - m) * rs * ggg[k] + bbb[k];
    zz = (zz >= 0.f) ? zz : SLOPE_C * zz;
    z[k] = zz * sc;
  }
  v.x = packbf(z[0], z[1]); v.y = packbf(z[2], z[3]);
  v.z = packbf(z[4], z[5]); v.w = packbf(z[6], z[7]);
  *reinterpret_cast<uint4*>(&outb[idx * 8]) = v;
}

// ---------------- final: BN apply + LayerNorm fused (DO=128, bf16 input) ----------------
__global__ __launch_bounds__(256) void bn_ln_kernel(
    const unsigned short* __restrict__ T, const float* __restrict__ colsum,
    const float* __restrict__ colsumsq, const float* __restrict__ g,
    const float* __restrict__ be, const float* __restrict__ lng,
    const float* __restrict__ lnb, float* __restrict__ out, float invN) {
  const int wave = threadIdx.x >> 6;
  const int lane = threadIdx.x & 63;
  const int n = blockIdx.x * 4 + wave;
  if (n >= N_NODES) return;
  const int c = lane * 2;
  const unsigned tv = *reinterpret_cast<const unsigned*>(&T[(size_t)n * 128 + c]);
  const float t0 = bflo(tv), t1 = bfhi(tv);
  float z[2];
#pragma unroll
  for (int k = 0; k < 2; ++k) {
    const float m = colsum[c + k] * invN;
    const float v = colsumsq[c + k] * invN - m * m;
    const float tvv = (k == 0) ? t0 : t1;
    z[k] = (tvv - m) * rsqrtf(v + EPS_C) * g[c + k] + be[c + k];
  }
  float s = z[0] + z[1];
  float q = z[0] * z[0] + z[1] * z[1];
  for (int o = 32; o > 0; o >>= 1) {
    s += __shfl_xor(s, o, 64);
    q += __shfl_xor(q, o, 64);
  }
  const float mean = s * (1.f / 128.f);
  const float var = q * (1.f / 128.f) - mean * mean;
  const float rs = rsqrtf(var + EPS_C);
  float2 o2;
  o2.x = (z[0] - mean) * rs * lng[c] + lnb[c];
  o2.y = (z[1] - mean) * rs * lng[c + 1] + lnb[c + 1];
  *reinterpret_cast<float2*>(&out[(size_t)n * 128 + c]) = o2;
}

extern "C" void kernel_launch(void* const* d_in, const int* in_sizes, int n_in,
                              void* d_out, int out_size, void* d_ws, size_t ws_size,
                              hipStream_t stream) {
  const float* x = (const float*)d_in[0];
  const int* ei = (const int*)d_in[1];
  const int* srcp = ei;
  const int* dstp = ei + N_EDGES;
  const float* W1 = (const float*)d_in[2];
  const float* b1 = (const float*)d_in[3];
  const float* g1 = (const float*)d_in[4];
  const float* be1 = (const float*)d_in[5];
  const float* W2 = (const float*)d_in[6];
  const float* b2 = (const float*)d_in[7];
  const float* g2 = (const float*)d_in[8];
  const float* be2 = (const float*)d_in[9];
  const float* W3 = (const float*)d_in[10];
  const float* b3 = (const float*)d_in[11];
  const float* g3 = (const float*)d_in[12];
  const float* be3 = (const float*)d_in[13];
  const float* W4 = (const float*)d_in[14];
  const float* b4 = (const float*)d_in[15];
  const float* g4 = (const float*)d_in[16];
  const float* be4 = (const float*)d_in[17];
  const float* lng = (const float*)d_in[18];
  const float* lnb = (const float*)d_in[19];
  float* out = (float*)d_out;

  char* ws = (char*)d_ws;
  size_t off_b = 0;
  auto alloc = [&](size_t bytes) -> void* {
    void* p = (void*)(ws + off_b);
    off_b += (bytes + 255) & ~(size_t)255;
    return p;
  };
  // ---- zero-region (one memset): hist + per-layer stats buffers ----
  int* hist = (int*)alloc((size_t)N_NODES * 4);
  float* cs1 = (float*)alloc(256 * 4);
  float* cq1 = (float*)alloc(256 * 4);
  float* cs2 = (float*)alloc(256 * 4);
  float* cq2 = (float*)alloc(256 * 4);
  float* cs3 = (float*)alloc(256 * 4);
  float* cq3 = (float*)alloc(256 * 4);
  float* cs4 = (float*)alloc(256 * 4);
  float* cq4 = (float*)alloc(256 * 4);
  const size_t zero_bytes = off_b;
  // ---- rest ----
  int* segoff = (int*)alloc((size_t)(N_NODES + 1) * 4);
  int* cursor = (int*)alloc((size_t)N_NODES * 4);
  float* nisq = (float*)alloc((size_t)N_NODES * 4);
  int* esorted = (int*)alloc((size_t)N_EDGES * 4);
  int* partial = (int*)alloc(64 * 4);
  int* partialoff = (int*)alloc(64 * 4);
  unsigned short* Wt1 = (unsigned short*)alloc((size_t)256 * 128 * 2);
  unsigned short* Wt2 = (unsigned short*)alloc((size_t)256 * 256 * 2);
  unsigned short* Wt3 = (unsigned short*)alloc((size_t)256 * 256 * 2);
  unsigned short* Wt4 = (unsigned short*)alloc((size_t)128 * 256 * 2);
  unsigned short* tblA = (unsigned short*)alloc((size_t)NPAD * 256 * 2);
  unsigned short* tblB = (unsigned short*)alloc((size_t)NPAD * 256 * 2);
  unsigned short* S = (unsigned short*)alloc((size_t)NPAD * 256 * 2);
  unsigned short* Tb = (unsigned short*)alloc((size_t)NPAD * 256 * 2);

  const float invN = 1.0f / (float)N_NODES;
  const int egrid = (N_EDGES + 255) / 256;
  const int ngrid = (N_NODES + 255) / 256;
  const int aggrid = NPAD / 4;             // covers pad rows (zero-writers)
  const int statgrid = (N_NODES + 127) / 128;
  const int nb = (N_NODES + 1023) / 1024;
  const dim3 mgrid256(NPAD / 128, 4);
  const dim3 mgrid128(NPAD / 128, 2);
  const unsigned bngrid = (unsigned)(((size_t)NPAD * 32 + 255) / 256);

  // ---- zero hist + all stats buffers in ONE memset ----
  hipMemsetAsync(hist, 0, zero_bytes, stream);

  // ---- degrees + nisq + dst-sorted edge list (counting sort) ----
  hist_kernel<<<egrid, 256, 0, stream>>>(dstp, hist, N_EDGES);
  scan1_kernel<<<nb, 1024, 0, stream>>>(hist, segoff, partial, nisq, N_NODES);
  scan2_kernel<<<1, 64, 0, stream>>>(partial, partialoff, &segoff[N_NODES], nb);
  scan3_kernel<<<ngrid, 256, 0, stream>>>(segoff, cursor, partialoff, N_NODES);
  scatter_kernel<<<egrid, 256, 0, stream>>>(srcp, dstp, cursor, esorted, N_EDGES);

  // ---- weights transpose+cast (one dispatch) ----
  wcast_all_kernel<<<dim3(256, 4), 256, 0, stream>>>(W1, W2, W3, W4, Wt1, Wt2, Wt3, Wt4);

  // ---- Layer 1: tblA = x*nisq; S = A_hat-gather; Tb = S W1 + b1 (+stats); bn*nisq -> tblB
  scale_cast_kernel<<<(N_NODES * 32 + 255) / 256, 256, 0, stream>>>(x, nisq, tblA);
  aggregate4_kernel<128, false, false, true><<<aggrid, 256, 0, stream>>>(
      tblA, segoff, esorted, nisq, nullptr, nullptr, S);
  gemm3_kernel<1, 128><<<mgrid256, 256, 0, stream>>>(S, Wt1, b1, Tb, cs1, cq1, 256);
  bn_lrelu_nisq_kernel<<<bngrid, 256, 0, stream>>>(Tb, cs1, cq1, g1, be1, nisq,
                                                   tblB, (size_t)NPAD * 32, invN);

  // ---- Layer 2 ----
  aggregate4_kernel<256, false, false, true><<<aggrid, 256, 0, stream>>>(
      tblB, segoff, esorted, nisq, nullptr, nullptr, S);
  gemm3_kernel<1, 256><<<mgrid256, 256, 0, stream>>>(S, Wt2, b2, Tb, cs2, cq2, 256);
  bn_lrelu_nisq_kernel<<<bngrid, 256, 0, stream>>>(Tb, cs2, cq2, g2, be2, nisq,
                                                   tblA, (size_t)NPAD * 32, invN);

  // ---- Layer 3 ----
  aggregate4_kernel<256, false, false, true><<<aggrid, 256, 0, stream>>>(
      tblA, segoff, esorted, nisq, nullptr, nullptr, S);
  gemm3_kernel<1, 256><<<mgrid256, 256, 0, stream>>>(S, Wt3, b3, Tb, cs3, cq3, 256);
  bn_lrelu_nisq_kernel<<<bngrid, 256, 0, stream>>>(Tb, cs3, cq3, g3, be3, nisq,
                                                   tblB, (size_t)NPAD * 32, invN);

  // ---- Layer 4: S = tblB·W4 (nisq pre-folded); agg(+b4+resid) -> bf16; stats; BN+LN ----
  gemm3_kernel<0, 256><<<mgrid128, 256, 0, stream>>>(tblB, Wt4, nullptr, S, nullptr, nullptr, 128);
  aggregate4_kernel<128, true, true, true><<<aggrid, 256, 0, stream>>>(
      S, segoff, esorted, nisq, b4, x, Tb);
  stats_bf16_kernel<<<statgrid, 128, 0, stream>>>(Tb, cs4, cq4, N_NODES, 128);
  bn_ln_kernel<<<(N_NODES + 3) / 4, 256, 0, stream>>>(Tb, cs4, cq4, g4, be4, lng, lnb, out, invN);
}

// Round 9
// 508.830 us; speedup vs baseline: 1.0212x; 1.0212x over previous
//
#include <hip/hip_runtime.h>

#define N_NODES 50000
#define NPAD 50176            // 392 * 128
#define N_EDGES 800000
#define EPS_C 1e-5f
#define SLOPE_C 0.01f

typedef __attribute__((ext_vector_type(8))) short short8v;
typedef __attribute__((ext_vector_type(4))) float f32x4;

// ---------- bf16 helpers (RNE) ----------
__device__ __forceinline__ unsigned short f2bf(float f) {
  unsigned u = __float_as_uint(f);
  u += 0x7fffu + ((u >> 16) & 1u);
  return (unsigned short)(u >> 16);
}
__device__ __forceinline__ unsigned packbf(float a, float b) {
  return (unsigned)f2bf(a) | ((unsigned)f2bf(b) << 16);
}
__device__ __forceinline__ float bflo(unsigned u) { return __uint_as_float(u << 16); }
__device__ __forceinline__ float bfhi(unsigned u) { return __uint_as_float(u & 0xffff0000u); }

// ---------- async global->LDS, 16 B per lane ----------
__device__ __forceinline__ void gload16(const unsigned short* g, unsigned short* l) {
  __builtin_amdgcn_global_load_lds(
      (const __attribute__((address_space(1))) unsigned int*)g,
      (__attribute__((address_space(3))) unsigned int*)l, 16, 0, 0);
}

// ---------------- fused: degree histogram + all-weights transpose/cast ----------------
#define HGRID 3125   // N_EDGES / 256
__global__ void hist_wcast_kernel(const int* __restrict__ dst, int* __restrict__ hist,
                                  const float* __restrict__ W1, const float* __restrict__ W2,
                                  const float* __restrict__ W3, const float* __restrict__ W4,
                                  unsigned short* __restrict__ Wt1, unsigned short* __restrict__ Wt2,
                                  unsigned short* __restrict__ Wt3, unsigned short* __restrict__ Wt4) {
  const int b = blockIdx.x;
  if (b < HGRID) {
    const int e = b * 256 + threadIdx.x;
    if (e < N_EDGES) atomicAdd(&hist[dst[e]], 1);
    return;
  }
  const int w = (b - HGRID) * 256 + threadIdx.x;  // [0, 196608)
  if (w < 32768) {
    Wt1[(size_t)(w & 255) * 128 + (w >> 8)] = f2bf(W1[w]);
  } else if (w < 98304) {
    const int v = w - 32768;
    Wt2[(size_t)(v & 255) * 256 + (v >> 8)] = f2bf(W2[v]);
  } else if (w < 163840) {
    const int v = w - 98304;
    Wt3[(size_t)(v & 255) * 256 + (v >> 8)] = f2bf(W3[v]);
  } else {
    const int v = w - 163840;
    Wt4[(size_t)(v & 127) * 256 + (v >> 7)] = f2bf(W4[v]);
  }
}

// ---------------- scan1: block-local exclusive scan + nisq ----------------
__global__ __launch_bounds__(1024) void scan1_kernel(
    const int* __restrict__ hist, int* __restrict__ off, int* __restrict__ partial,
    float* __restrict__ nisq, int n) {
  __shared__ int tmp[1024];
  const int tid = threadIdx.x;
  const int i = blockIdx.x * 1024 + tid;
  const int v = (i < n) ? hist[i] : 0;
  tmp[tid] = v;
  __syncthreads();
  int x = v;
  for (int o = 1; o < 1024; o <<= 1) {
    const int y = (tid >= o) ? tmp[tid - o] : 0;
    __syncthreads();
    x += y;
    tmp[tid] = x;
    __syncthreads();
  }
  if (i < n) {
    off[i] = x - v;
    nisq[i] = rsqrtf((float)v + 1.0f);
  }
  if (tid == 1023) partial[blockIdx.x] = x;
}

// ---------------- fused: scan finalize (inline partial prefix) + scale_cast ----------------
#define SGRID 196    // ceil(N_NODES/256)
#define NBCH 49      // ceil(N_NODES/1024)
__global__ void scan3f_kernel(int* __restrict__ off, int* __restrict__ cursor,
                              const int* __restrict__ partial,
                              const float* __restrict__ nisq, const float* __restrict__ x,
                              unsigned short* __restrict__ xs) {
  const int b = blockIdx.x;
  if (b < SGRID) {
    const int i = b * 256 + threadIdx.x;
    const int chunk = b >> 2;
    int pre = 0;
    for (int k = 0; k < chunk; ++k) pre += partial[k];
    if (i < N_NODES) {
      const int o = off[i] + pre;
      off[i] = o;
      cursor[i] = o;
    }
    if (b == SGRID - 1 && threadIdx.x == 0)
      off[N_NODES] = pre + partial[NBCH - 1];
    return;
  }
  const int idx = (b - SGRID) * 256 + threadIdx.x;  // scale_cast: 6250 blocks
  if (idx >= N_NODES * 32) return;
  const int row = idx >> 5;
  const int c = (idx & 31) * 4;
  const float s = nisq[row];
  const float4 v = *reinterpret_cast<const float4*>(&x[(size_t)row * 128 + c]);
  ushort4 o;
  o.x = f2bf(v.x * s); o.y = f2bf(v.y * s);
  o.z = f2bf(v.z * s); o.w = f2bf(v.w * s);
  *reinterpret_cast<ushort4*>(&xs[(size_t)row * 128 + c]) = o;
}

// ---------------- scatter edges into dst-sorted order ----------------
__global__ void scatter_kernel(const int* __restrict__ src, const int* __restrict__ dst,
                               int* __restrict__ cursor, int* __restrict__ esorted, int E) {
  const int e = blockIdx.x * 256 + threadIdx.x;
  if (e < E) {
    const int p = atomicAdd(&cursor[dst[e]], 1);
    esorted[p] = src[e];
  }
}

// ---------------- MFMA GEMM (r7-proven): persistent swizzled B panel + global_load_lds A ----
// A: NPAD x KC bf16 (pad rows zero). Wt: M x KC bf16.
// MODE 0: Yb = bf16(A·Wt^T)          MODE 1: Yb = bf16(A·Wt^T + bias) + fused col stats
template <int MODE, int KC>
__global__ __launch_bounds__(256) void gemm2_kernel(
    const unsigned short* __restrict__ A, const unsigned short* __restrict__ Wt,
    const float* __restrict__ bias, unsigned short* __restrict__ Yb,
    float* __restrict__ colsum, float* __restrict__ colsumsq, int M) {
  __shared__ __align__(16) unsigned short Bs[64][KC];   // swizzled
  __shared__ __align__(16) unsigned short As[128][64];  // swizzled (linear dest, src-swizzled)
  __shared__ float sred[2][64][2];
  const int tid = threadIdx.x;
  const int lane = tid & 63;
  const int wave = tid >> 6;
  const int wr = wave >> 1, wc = wave & 1;
  const int row0 = blockIdx.x * 128;
  const int col0 = blockIdx.y * 64;
  const int l15 = lane & 15;
  const int lhi = lane >> 4;

  // ---- stage full B panel once (64 cols x KC), XOR-swizzled chunks ----
  constexpr int CPR = KC / 8;
  constexpr int BITER = 64 * CPR / 256;
#pragma unroll
  for (int c = 0; c < BITER; ++c) {
    const int ch = c * 256 + tid;
    const int rb = ch / CPR;
    const int cb = ch % CPR;
    const short8v v =
        *reinterpret_cast<const short8v*>(&Wt[(size_t)(col0 + rb) * KC + cb * 8]);
    *reinterpret_cast<short8v*>(&Bs[rb][(cb ^ (rb & 7)) * 8]) = v;
  }

  f32x4 acc[4][2];
#pragma unroll
  for (int i = 0; i < 4; ++i)
#pragma unroll
    for (int j = 0; j < 2; ++j) acc[i][j] = (f32x4){0.f, 0.f, 0.f, 0.f};

  for (int k0 = 0; k0 < KC; k0 += 64) {
    __syncthreads();  // previous step's readers done (also orders B writes on iter 0)
    // ---- issue A tile staging: 1024 x 16B chunks, LDS linear, global src pre-swizzled ----
#pragma unroll
    for (int c = 0; c < 4; ++c) {
      const int chunk = (c * 4 + wave) * 64 + lane;
      const int r = chunk >> 3;
      const int cksrc = (chunk & 7) ^ (r & 7);
      gload16(&A[(size_t)(row0 + r) * KC + k0 + cksrc * 8], &As[0][0] + chunk * 8);
    }
    __syncthreads();  // drains vmcnt: A tile resident
    // ---- MFMA ----
    short8v bfr[2][2];
#pragma unroll
    for (int nr = 0; nr < 2; ++nr)
#pragma unroll
      for (int h = 0; h < 2; ++h) {
        const int rowb = wc * 32 + nr * 16 + l15;
        const int chb = (k0 >> 3) + h * 4 + lhi;
        bfr[nr][h] = *reinterpret_cast<const short8v*>(&Bs[rowb][(chb ^ (rowb & 7)) * 8]);
      }
#pragma unroll
    for (int mr = 0; mr < 4; ++mr) {
#pragma unroll
      for (int h = 0; h < 2; ++h) {
        const int rowa = wr * 64 + mr * 16 + l15;
        const int cha = (h * 4 + lhi) ^ (rowa & 7);
        const short8v af = *reinterpret_cast<const short8v*>(&As[rowa][cha * 8]);
#pragma unroll
        for (int nr = 0; nr < 2; ++nr)
          acc[mr][nr] = __builtin_amdgcn_mfma_f32_16x16x32_bf16(
              af, bfr[nr][h], acc[mr][nr], 0, 0, 0);
      }
    }
  }
  // ---- epilogue: unguarded stores (pads zero+harmless); stats guarded to real rows ----
  float bcol[2] = {0.f, 0.f};
  if constexpr (MODE == 1) {
#pragma unroll
    for (int nr = 0; nr < 2; ++nr) bcol[nr] = bias[col0 + wc * 32 + nr * 16 + l15];
  }
  float s_c[2] = {0.f, 0.f}, q_c[2] = {0.f, 0.f};
#pragma unroll
  for (int mr = 0; mr < 4; ++mr) {
#pragma unroll
    for (int r = 0; r < 4; ++r) {
      const int grow = row0 + wr * 64 + mr * 16 + lhi * 4 + r;
#pragma unroll
      for (int nr = 0; nr < 2; ++nr) {
        const int gcol = col0 + wc * 32 + nr * 16 + l15;
        const float v = acc[mr][nr][r] + bcol[nr];
        Yb[(size_t)grow * M + gcol] = f2bf(v);
        if constexpr (MODE == 1) {
          if (grow < N_NODES) {
            s_c[nr] += v;
            q_c[nr] += v * v;
          }
        }
      }
    }
  }
  if constexpr (MODE == 1) {
#pragma unroll
    for (int nr = 0; nr < 2; ++nr) {
      float s = s_c[nr], q = q_c[nr];
      s += __shfl_xor(s, 16, 64); q += __shfl_xor(q, 16, 64);
      s += __shfl_xor(s, 32, 64); q += __shfl_xor(q, 32, 64);
      if (lhi == 0) {
        const int cl = wc * 32 + nr * 16 + l15;
        sred[0][cl][wr] = s;
        sred[1][cl][wr] = q;
      }
    }
    __syncthreads();
    if (tid < 128) {
      const int which = tid >> 6;
      const int cl = tid & 63;
      const float tot = sred[which][cl][0] + sred[which][cl][1];
      float* dstp = which ? colsumsq : colsum;
      atomicAdd(&dstp[col0 + cl], tot);
    }
  }
}

// ---------------- pure gather aggregation (half-wave, 16B/lane); zeroes pad rows ----------------
template <int DO, bool ADD_BIAS, bool HAS_RES, bool OUT_BF16>
__global__ __launch_bounds__(256) void aggregate4_kernel(
    const unsigned short* __restrict__ Y, const int* __restrict__ segoff,
    const int* __restrict__ esorted, const float* __restrict__ nisq,
    const float* __restrict__ bias, const float* __restrict__ resid,
    void* __restrict__ Tv) {
  constexpr int V2 = DO / 32;  // bf16 elems per lane per row (128: 4, 256: 8)
  const int wave = threadIdx.x >> 6;
  const int lane = threadIdx.x & 63;
  const int half = lane >> 5;
  const int l31 = lane & 31;
  const int n = blockIdx.x * 4 + wave;
  const int colbase = l31 * V2;
  if (n >= N_NODES) {  // pad row: write zeros so GEMM can load unguarded
    if (half == 0) {
      if constexpr (OUT_BF16) {
        unsigned short* tr = (unsigned short*)Tv + (size_t)n * DO + colbase;
        if constexpr (V2 == 8) *reinterpret_cast<uint4*>(tr) = (uint4){0, 0, 0, 0};
        else *reinterpret_cast<uint2*>(tr) = (uint2){0, 0};
      } else {
        float* tr = (float*)Tv + (size_t)n * DO + colbase;
        if constexpr (V2 == 8) {
          *reinterpret_cast<float4*>(tr) = (float4){0.f, 0.f, 0.f, 0.f};
          *reinterpret_cast<float4*>(tr + 4) = (float4){0.f, 0.f, 0.f, 0.f};
        } else {
          *reinterpret_cast<float4*>(tr) = (float4){0.f, 0.f, 0.f, 0.f};
        }
      }
    }
    return;
  }
  const unsigned short* Yc = Y + colbase;
  float a0[V2], a1[V2];
#pragma unroll
  for (int i = 0; i < V2; ++i) { a0[i] = 0.f; a1[i] = 0.f; }
  const int s = segoff[n];
  const int e = segoff[n + 1];

  if constexpr (V2 == 8) {
    auto acc8 = [&](float* a, const uint4 v) {
      a[0] += bflo(v.x); a[1] += bfhi(v.x);
      a[2] += bflo(v.y); a[3] += bfhi(v.y);
      a[4] += bflo(v.z); a[5] += bfhi(v.z);
      a[6] += bflo(v.w); a[7] += bfhi(v.w);
    };
    int j = s + half;
    for (; j + 2 < e; j += 4) {
      const int i0 = esorted[j];
      const int i1 = esorted[j + 2];
      const uint4 v0 = *reinterpret_cast<const uint4*>(Yc + (size_t)i0 * DO);
      const uint4 v1 = *reinterpret_cast<const uint4*>(Yc + (size_t)i1 * DO);
      acc8(a0, v0); acc8(a1, v1);
    }
    if (j < e) acc8(a0, *reinterpret_cast<const uint4*>(Yc + (size_t)esorted[j] * DO));
    if (half == 0) acc8(a1, *reinterpret_cast<const uint4*>(Yc + (size_t)n * DO));
  } else {
    auto acc4 = [&](float* a, const uint2 v) {
      a[0] += bflo(v.x); a[1] += bfhi(v.x);
      a[2] += bflo(v.y); a[3] += bfhi(v.y);
    };
    int j = s + half;
    for (; j + 2 < e; j += 4) {
      const int i0 = esorted[j];
      const int i1 = esorted[j + 2];
      const uint2 v0 = *reinterpret_cast<const uint2*>(Yc + (size_t)i0 * DO);
      const uint2 v1 = *reinterpret_cast<const uint2*>(Yc + (size_t)i1 * DO);
      acc4(a0, v0); acc4(a1, v1);
    }
    if (j < e) acc4(a0, *reinterpret_cast<const uint2*>(Yc + (size_t)esorted[j] * DO));
    if (half == 0) acc4(a1, *reinterpret_cast<const uint2*>(Yc + (size_t)n * DO));
  }

  const float sc = nisq[n];
  float vals[V2];
#pragma unroll
  for (int i = 0; i < V2; ++i) {
    float t = a0[i] + a1[i];
    t += __shfl_xor(t, 32, 64);
    t *= sc;
    if (half == 0) {
      if (ADD_BIAS) t += bias[colbase + i];
      if (HAS_RES) t += resid[(size_t)n * DO + colbase + i];
    }
    vals[i] = t;
  }
  if (half == 0) {
    if constexpr (OUT_BF16) {
      unsigned short* tr = (unsigned short*)Tv + (size_t)n * DO + colbase;
      if constexpr (V2 == 8) {
        uint4 o;
        o.x = packbf(vals[0], vals[1]); o.y = packbf(vals[2], vals[3]);
        o.z = packbf(vals[4], vals[5]); o.w = packbf(vals[6], vals[7]);
        *reinterpret_cast<uint4*>(tr) = o;
      } else {
        uint2 o;
        o.x = packbf(vals[0], vals[1]); o.y = packbf(vals[2], vals[3]);
        *reinterpret_cast<uint2*>(tr) = o;
      }
    } else {
      float* tr = (float*)Tv + (size_t)n * DO + colbase;
      if constexpr (V2 == 8) {
        float4 o0 = {vals[0], vals[1], vals[2], vals[3]};
        float4 o1 = {vals[4], vals[5], vals[6], vals[7]};
        *reinterpret_cast<float4*>(tr) = o0;
        *reinterpret_cast<float4*>(tr + 4) = o1;
      } else {
        float4 o = {vals[0], vals[1], vals[2], vals[3]};
        *reinterpret_cast<float4*>(tr) = o;
      }
    }
  }
}

// ---------------- column sums for BN stats (bf16 input, L4 only) ----------------
__global__ void stats_bf16_kernel(const unsigned short* __restrict__ T,
                                  float* __restrict__ colsum, float* __restrict__ colsumsq,
                                  int n, int rowsPerBlock) {
  const int t = threadIdx.x;   // 128 threads; thread handles 2 cols (one uint) over half rows
  const int c2 = t & 63;
  const int rh = t >> 6;
  const int r0 = blockIdx.x * rowsPerBlock;
  int r1 = r0 + rowsPerBlock;
  if (r1 > n) r1 = n;
  const unsigned* T32 = (const unsigned*)T;
  float s0 = 0.f, q0 = 0.f, s1 = 0.f, q1 = 0.f;
  for (int r = r0 + rh; r < r1; r += 2) {
    const unsigned v = T32[(size_t)r * 64 + c2];
    const float a = bflo(v), b = bfhi(v);
    s0 += a; q0 += a * a;
    s1 += b; q1 += b * b;
  }
  atomicAdd(&colsum[c2 * 2], s0);
  atomicAdd(&colsumsq[c2 * 2], q0);
  atomicAdd(&colsum[c2 * 2 + 1], s1);
  atomicAdd(&colsumsq[c2 * 2 + 1], q1);
}

// ---------------- BN apply + LeakyReLU + nisq row-scale, bf16 -> bf16 (DO=256); zero pads ----
__global__ void bn_lrelu_nisq_kernel(const unsigned short* __restrict__ Tb,
                                     const float* __restrict__ colsum,
                                     const float* __restrict__ colsumsq,
                                     const float* __restrict__ g, const float* __restrict__ be,
                                     const float* __restrict__ nisq,
                                     unsigned short* __restrict__ outb,
                                     size_t total8, float invN) {
  const size_t idx = (size_t)blockIdx.x * 256 + threadIdx.x;
  if (idx >= total8) return;
  const int row = (int)(idx >> 5);
  if (row >= N_NODES) {  // pad row: table must stay zero for next GEMM
    *reinterpret_cast<uint4*>(&outb[idx * 8]) = (uint4){0, 0, 0, 0};
    return;
  }
  const unsigned c = ((unsigned)idx & 31u) * 8;
  const float sc = nisq[row];
  uint4 v = *reinterpret_cast<const uint4*>(&Tb[idx * 8]);
  float z[8] = {bflo(v.x), bfhi(v.x), bflo(v.y), bfhi(v.y),
                bflo(v.z), bfhi(v.z), bflo(v.w), bfhi(v.w)};
  const float4 cs0 = *reinterpret_cast<const float4*>(&colsum[c]);
  const float4 cs1 = *reinterpret_cast<const float4*>(&colsum[c + 4]);
  const float4 cq0 = *reinterpret_cast<const float4*>(&colsumsq[c]);
  const float4 cq1 = *reinterpret_cast<const float4*>(&colsumsq[c + 4]);
  const float4 gv0 = *reinterpret_cast<const float4*>(&g[c]);
  const float4 gv1 = *reinterpret_cast<const float4*>(&g[c + 4]);
  const float4 bv0 = *reinterpret_cast<const float4*>(&be[c]);
  const float4 bv1 = *reinterpret_cast<const float4*>(&be[c + 4]);
  const float css[8] = {cs0.x, cs0.y, cs0.z, cs0.w, cs1.x, cs1.y, cs1.z, cs1.w};
  const float cqq[8] = {cq0.x, cq0.y, cq0.z, cq0.w, cq1.x, cq1.y, cq1.z, cq1.w};
  const float ggg[8] = {gv0.x, gv0.y, gv0.z, gv0.w, gv1.x, gv1.y, gv1.z, gv1.w};
  const float bbb[8] = {bv0.x, bv0.y, bv0.z, bv0.w, bv1.x, bv1.y, bv1.z, bv1.w};
#pragma unroll
  for (int k = 0; k < 8; ++k) {
    const float m = css[k] * invN;
    const float rs = rsqrtf(cqq[k] * invN - m * m + EPS_C);
    float zz = (z[k] - m) * rs * ggg[k] + bbb[k];
    zz = (zz >= 0.f) ? zz : SLOPE_C * zz;
    z[k] = zz * sc;
  }
  v.x = packbf(z[0], z[1]); v.y = packbf(z[2], z[3]);
  v.z = packbf(z[4], z[5]); v.w = packbf(z[6], z[7]);
  *reinterpret_cast<uint4*>(&outb[idx * 8]) = v;
}

// ---------------- final: BN apply + LayerNorm fused (DO=128, bf16 input) ----------------
__global__ __launch_bounds__(256) void bn_ln_kernel(
    const unsigned short* __restrict__ T, const float* __restrict__ colsum,
    const float* __restrict__ colsumsq, const float* __restrict__ g,
    const float* __restrict__ be, const float* __restrict__ lng,
    const float* __restrict__ lnb, float* __restrict__ out, float invN) {
  const int wave = threadIdx.x >> 6;
  const int lane = threadIdx.x & 63;
  const int n = blockIdx.x * 4 + wave;
  if (n >= N_NODES) return;
  const int c = lane * 2;
  const unsigned tv = *reinterpret_cast<const unsigned*>(&T[(size_t)n * 128 + c]);
  const float t0 = bflo(tv), t1 = bfhi(tv);
  float z[2];
#pragma unroll
  for (int k = 0; k < 2; ++k) {
    const float m = colsum[c + k] * invN;
    const float v = colsumsq[c + k] * invN - m * m;
    const float tvv = (k == 0) ? t0 : t1;
    z[k] = (tvv - m) * rsqrtf(v + EPS_C) * g[c + k] + be[c + k];
  }
  float s = z[0] + z[1];
  float q = z[0] * z[0] + z[1] * z[1];
  for (int o = 32; o > 0; o >>= 1) {
    s += __shfl_xor(s, o, 64);
    q += __shfl_xor(q, o, 64);
  }
  const float mean = s * (1.f / 128.f);
  const float var = q * (1.f / 128.f) - mean * mean;
  const float rs = rsqrtf(var + EPS_C);
  float2 o2;
  o2.x = (z[0] - mean) * rs * lng[c] + lnb[c];
  o2.y = (z[1] - mean) * rs * lng[c + 1] + lnb[c + 1];
  *reinterpret_cast<float2*>(&out[(size_t)n * 128 + c]) = o2;
}

extern "C" void kernel_launch(void* const* d_in, const int* in_sizes, int n_in,
                              void* d_out, int out_size, void* d_ws, size_t ws_size,
                              hipStream_t stream) {
  const float* x = (const float*)d_in[0];
  const int* ei = (const int*)d_in[1];
  const int* srcp = ei;
  const int* dstp = ei + N_EDGES;
  const float* W1 = (const float*)d_in[2];
  const float* b1 = (const float*)d_in[3];
  const float* g1 = (const float*)d_in[4];
  const float* be1 = (const float*)d_in[5];
  const float* W2 = (const float*)d_in[6];
  const float* b2 = (const float*)d_in[7];
  const float* g2 = (const float*)d_in[8];
  const float* be2 = (const float*)d_in[9];
  const float* W3 = (const float*)d_in[10];
  const float* b3 = (const float*)d_in[11];
  const float* g3 = (const float*)d_in[12];
  const float* be3 = (const float*)d_in[13];
  const float* W4 = (const float*)d_in[14];
  const float* b4 = (const float*)d_in[15];
  const float* g4 = (const float*)d_in[16];
  const float* be4 = (const float*)d_in[17];
  const float* lng = (const float*)d_in[18];
  const float* lnb = (const float*)d_in[19];
  float* out = (float*)d_out;

  char* ws = (char*)d_ws;
  size_t off_b = 0;
  auto alloc = [&](size_t bytes) -> void* {
    void* p = (void*)(ws + off_b);
    off_b += (bytes + 255) & ~(size_t)255;
    return p;
  };
  // ---- zero-region (one memset): hist + per-layer stats buffers ----
  int* hist = (int*)alloc((size_t)N_NODES * 4);
  float* cs1 = (float*)alloc(256 * 4);
  float* cq1 = (float*)alloc(256 * 4);
  float* cs2 = (float*)alloc(256 * 4);
  float* cq2 = (float*)alloc(256 * 4);
  float* cs3 = (float*)alloc(256 * 4);
  float* cq3 = (float*)alloc(256 * 4);
  float* cs4 = (float*)alloc(256 * 4);
  float* cq4 = (float*)alloc(256 * 4);
  const size_t zero_bytes = off_b;
  // ---- rest ----
  int* segoff = (int*)alloc((size_t)(N_NODES + 1) * 4);
  int* cursor = (int*)alloc((size_t)N_NODES * 4);
  float* nisq = (float*)alloc((size_t)N_NODES * 4);
  int* esorted = (int*)alloc((size_t)N_EDGES * 4);
  int* partial = (int*)alloc(64 * 4);
  unsigned short* Wt1 = (unsigned short*)alloc((size_t)256 * 128 * 2);
  unsigned short* Wt2 = (unsigned short*)alloc((size_t)256 * 256 * 2);
  unsigned short* Wt3 = (unsigned short*)alloc((size_t)256 * 256 * 2);
  unsigned short* Wt4 = (unsigned short*)alloc((size_t)128 * 256 * 2);
  unsigned short* tblA = (unsigned short*)alloc((size_t)NPAD * 256 * 2);
  unsigned short* tblB = (unsigned short*)alloc((size_t)NPAD * 256 * 2);
  unsigned short* S = (unsigned short*)alloc((size_t)NPAD * 256 * 2);
  unsigned short* Tb = (unsigned short*)alloc((size_t)NPAD * 256 * 2);

  const float invN = 1.0f / (float)N_NODES;
  const int egrid = (N_EDGES + 255) / 256;      // 3125
  const int aggrid = NPAD / 4;                  // covers pad rows (zero-writers)
  const int statgrid = (N_NODES + 127) / 128;
  const dim3 mgrid256(NPAD / 128, 4);
  const dim3 mgrid128(NPAD / 128, 2);
  const unsigned bngrid = (unsigned)(((size_t)NPAD * 32 + 255) / 256);

  // ---- zero hist + all stats buffers in ONE memset ----
  hipMemsetAsync(hist, 0, zero_bytes, stream);

  // ---- fused: degrees + weight transpose/cast ----
  hist_wcast_kernel<<<HGRID + 768, 256, 0, stream>>>(dstp, hist, W1, W2, W3, W4,
                                                     Wt1, Wt2, Wt3, Wt4);
  scan1_kernel<<<NBCH, 1024, 0, stream>>>(hist, segoff, partial, nisq, N_NODES);
  // ---- fused: scan finalize + scale_cast (tblA = bf16(x*nisq)) ----
  scan3f_kernel<<<SGRID + 6250, 256, 0, stream>>>(segoff, cursor, partial, nisq, x, tblA);
  scatter_kernel<<<egrid, 256, 0, stream>>>(srcp, dstp, cursor, esorted, N_EDGES);

  // ---- Layer 1: S = A_hat-gather(tblA); Tb = S W1 + b1 (+stats); bn*nisq -> tblB ----
  aggregate4_kernel<128, false, false, true><<<aggrid, 256, 0, stream>>>(
      tblA, segoff, esorted, nisq, nullptr, nullptr, S);
  gemm2_kernel<1, 128><<<mgrid256, 256, 0, stream>>>(S, Wt1, b1, Tb, cs1, cq1, 256);
  bn_lrelu_nisq_kernel<<<bngrid, 256, 0, stream>>>(Tb, cs1, cq1, g1, be1, nisq,
                                                   tblB, (size_t)NPAD * 32, invN);

  // ---- Layer 2 ----
  aggregate4_kernel<256, false, false, true><<<aggrid, 256, 0, stream>>>(
      tblB, segoff, esorted, nisq, nullptr, nullptr, S);
  gemm2_kernel<1, 256><<<mgrid256, 256, 0, stream>>>(S, Wt2, b2, Tb, cs2, cq2, 256);
  bn_lrelu_nisq_kernel<<<bngrid, 256, 0, stream>>>(Tb, cs2, cq2, g2, be2, nisq,
                                                   tblA, (size_t)NPAD * 32, invN);

  // ---- Layer 3 ----
  aggregate4_kernel<256, false, false, true><<<aggrid, 256, 0, stream>>>(
      tblA, segoff, esorted, nisq, nullptr, nullptr, S);
  gemm2_kernel<1, 256><<<mgrid256, 256, 0, stream>>>(S, Wt3, b3, Tb, cs3, cq3, 256);
  bn_lrelu_nisq_kernel<<<bngrid, 256, 0, stream>>>(Tb, cs3, cq3, g3, be3, nisq,
                                                   tblB, (size_t)NPAD * 32, invN);

  // ---- Layer 4: S = tblB·W4 (nisq pre-folded); agg(+b4+resid) -> bf16; stats; BN+LN ----
  gemm2_kernel<0, 256><<<mgrid128, 256, 0, stream>>>(tblB, Wt4, nullptr, S, nullptr, nullptr, 128);
  aggregate4_kernel<128, true, true, true><<<aggrid, 256, 0, stream>>>(
      S, segoff, esorted, nisq, b4, x, Tb);
  stats_bf16_kernel<<<statgrid, 128, 0, stream>>>(Tb, cs4, cq4, N_NODES, 128);
  bn_ln_kernel<<<(N_NODES + 3) / 4, 256, 0, stream>>>(Tb, cs4, cq4, g4, be4, lng, lnb, out, invN);
}

// Round 10
// 478.149 us; speedup vs baseline: 1.0867x; 1.0642x over previous
//
#include <hip/hip_runtime.h>

#define N_NODES 50000
#define NPAD 50176            // 392 * 128
#define N_EDGES 800000
#define EPS_C 1e-5f
#define SLOPE_C 0.01f

typedef __attribute__((ext_vector_type(8))) short short8v;
typedef __attribute__((ext_vector_type(4))) float f32x4;

// ---------- bf16 helpers (RNE) ----------
__device__ __forceinline__ unsigned short f2bf(float f) {
  unsigned u = __float_as_uint(f);
  u += 0x7fffu + ((u >> 16) & 1u);
  return (unsigned short)(u >> 16);
}
__device__ __forceinline__ unsigned packbf(float a, float b) {
  return (unsigned)f2bf(a) | ((unsigned)f2bf(b) << 16);
}
__device__ __forceinline__ float bflo(unsigned u) { return __uint_as_float(u << 16); }
__device__ __forceinline__ float bfhi(unsigned u) { return __uint_as_float(u & 0xffff0000u); }

// ---------- async global->LDS, 16 B per lane ----------
__device__ __forceinline__ void gload16(const unsigned short* g, unsigned short* l) {
  __builtin_amdgcn_global_load_lds(
      (const __attribute__((address_space(1))) unsigned int*)g,
      (__attribute__((address_space(3))) unsigned int*)l, 16, 0, 0);
}

// ---------------- fused: degree histogram + all-weights transpose/cast ----------------
#define HGRID 3125   // N_EDGES / 256
__global__ void hist_wcast_kernel(const int* __restrict__ dst, int* __restrict__ hist,
                                  const float* __restrict__ W1, const float* __restrict__ W2,
                                  const float* __restrict__ W3, const float* __restrict__ W4,
                                  unsigned short* __restrict__ Wt1, unsigned short* __restrict__ Wt2,
                                  unsigned short* __restrict__ Wt3, unsigned short* __restrict__ Wt4) {
  const int b = blockIdx.x;
  if (b < HGRID) {
    const int e = b * 256 + threadIdx.x;
    if (e < N_EDGES) atomicAdd(&hist[dst[e]], 1);
    return;
  }
  const int w = (b - HGRID) * 256 + threadIdx.x;  // [0, 196608)
  if (w < 32768) {
    Wt1[(size_t)(w & 255) * 128 + (w >> 8)] = f2bf(W1[w]);
  } else if (w < 98304) {
    const int v = w - 32768;
    Wt2[(size_t)(v & 255) * 256 + (v >> 8)] = f2bf(W2[v]);
  } else if (w < 163840) {
    const int v = w - 98304;
    Wt3[(size_t)(v & 255) * 256 + (v >> 8)] = f2bf(W3[v]);
  } else {
    const int v = w - 163840;
    Wt4[(size_t)(v & 127) * 256 + (v >> 7)] = f2bf(W4[v]);
  }
}

// ---------------- scan1: block-local exclusive scan + nisq ----------------
__global__ __launch_bounds__(1024) void scan1_kernel(
    const int* __restrict__ hist, int* __restrict__ off, int* __restrict__ partial,
    float* __restrict__ nisq, int n) {
  __shared__ int tmp[1024];
  const int tid = threadIdx.x;
  const int i = blockIdx.x * 1024 + tid;
  const int v = (i < n) ? hist[i] : 0;
  tmp[tid] = v;
  __syncthreads();
  int x = v;
  for (int o = 1; o < 1024; o <<= 1) {
    const int y = (tid >= o) ? tmp[tid - o] : 0;
    __syncthreads();
    x += y;
    tmp[tid] = x;
    __syncthreads();
  }
  if (i < n) {
    off[i] = x - v;
    nisq[i] = rsqrtf((float)v + 1.0f);
  }
  if (tid == 1023) partial[blockIdx.x] = x;
}

// ---------------- fused: scan finalize (inline partial prefix) + scale_cast ----------------
#define SGRID 196    // ceil(N_NODES/256)
#define NBCH 49      // ceil(N_NODES/1024)
__global__ void scan3f_kernel(int* __restrict__ off, int* __restrict__ cursor,
                              const int* __restrict__ partial,
                              const float* __restrict__ nisq, const float* __restrict__ x,
                              unsigned short* __restrict__ xs) {
  const int b = blockIdx.x;
  if (b < SGRID) {
    const int i = b * 256 + threadIdx.x;
    const int chunk = b >> 2;
    int pre = 0;
    for (int k = 0; k < chunk; ++k) pre += partial[k];
    if (i < N_NODES) {
      const int o = off[i] + pre;
      off[i] = o;
      cursor[i] = o;
    }
    if (b == SGRID - 1 && threadIdx.x == 0)
      off[N_NODES] = pre + partial[NBCH - 1];
    return;
  }
  const int idx = (b - SGRID) * 256 + threadIdx.x;  // scale_cast: 6250 blocks
  if (idx >= N_NODES * 32) return;
  const int row = idx >> 5;
  const int c = (idx & 31) * 4;
  const float s = nisq[row];
  const float4 v = *reinterpret_cast<const float4*>(&x[(size_t)row * 128 + c]);
  ushort4 o;
  o.x = f2bf(v.x * s); o.y = f2bf(v.y * s);
  o.z = f2bf(v.z * s); o.w = f2bf(v.w * s);
  *reinterpret_cast<ushort4*>(&xs[(size_t)row * 128 + c]) = o;
}

// ---------------- scatter edges into dst-sorted order ----------------
__global__ void scatter_kernel(const int* __restrict__ src, const int* __restrict__ dst,
                               int* __restrict__ cursor, int* __restrict__ esorted, int E) {
  const int e = blockIdx.x * 256 + threadIdx.x;
  if (e < E) {
    const int p = atomicAdd(&cursor[dst[e]], 1);
    esorted[p] = src[e];
  }
}

// ---------------- MFMA GEMM: persistent swizzled B panel + global_load_lds A ----------------
// 1-D grid, col-fastest block order + bijective XCD chunking: each XCD chunk covers
// 49 row-blocks x all col-panels contiguously -> A window ~3.2MB fits per-XCD L2,
// A is fetched ~once instead of once per col-panel.
// A: NPAD x KC bf16 (pad rows zero). Wt: M x KC bf16.
// MODE 0: Yb = bf16(A·Wt^T)          MODE 1: Yb = bf16(A·Wt^T + bias) + fused col stats
template <int MODE, int KC, int NCOL_LOG2>
__global__ __launch_bounds__(256) void gemm2_kernel(
    const unsigned short* __restrict__ A, const unsigned short* __restrict__ Wt,
    const float* __restrict__ bias, unsigned short* __restrict__ Yb,
    float* __restrict__ colsum, float* __restrict__ colsumsq, int M) {
  __shared__ __align__(16) unsigned short Bs[64][KC];   // swizzled
  __shared__ __align__(16) unsigned short As[128][64];  // swizzled (linear dest, src-swizzled)
  __shared__ float sred[2][64][2];
  const int tid = threadIdx.x;
  const int lane = tid & 63;
  const int wave = tid >> 6;
  const int wr = wave >> 1, wc = wave & 1;
  // XCD-chunked, col-fastest block mapping (gridDim.x % 8 == 0 by construction)
  const int chunkN = gridDim.x >> 3;
  const int swz = (blockIdx.x & 7) * chunkN + (blockIdx.x >> 3);
  const int row0 = (swz >> NCOL_LOG2) * 128;
  const int col0 = (swz & ((1 << NCOL_LOG2) - 1)) * 64;
  const int l15 = lane & 15;
  const int lhi = lane >> 4;

  // ---- stage full B panel once (64 cols x KC), XOR-swizzled chunks ----
  constexpr int CPR = KC / 8;
  constexpr int BITER = 64 * CPR / 256;
#pragma unroll
  for (int c = 0; c < BITER; ++c) {
    const int ch = c * 256 + tid;
    const int rb = ch / CPR;
    const int cb = ch % CPR;
    const short8v v =
        *reinterpret_cast<const short8v*>(&Wt[(size_t)(col0 + rb) * KC + cb * 8]);
    *reinterpret_cast<short8v*>(&Bs[rb][(cb ^ (rb & 7)) * 8]) = v;
  }

  f32x4 acc[4][2];
#pragma unroll
  for (int i = 0; i < 4; ++i)
#pragma unroll
    for (int j = 0; j < 2; ++j) acc[i][j] = (f32x4){0.f, 0.f, 0.f, 0.f};

  for (int k0 = 0; k0 < KC; k0 += 64) {
    __syncthreads();  // previous step's readers done (also orders B writes on iter 0)
    // ---- issue A tile staging: 1024 x 16B chunks, LDS linear, global src pre-swizzled ----
#pragma unroll
    for (int c = 0; c < 4; ++c) {
      const int chunk = (c * 4 + wave) * 64 + lane;
      const int r = chunk >> 3;
      const int cksrc = (chunk & 7) ^ (r & 7);
      gload16(&A[(size_t)(row0 + r) * KC + k0 + cksrc * 8], &As[0][0] + chunk * 8);
    }
    __syncthreads();  // drains vmcnt: A tile resident
    // ---- MFMA ----
    short8v bfr[2][2];
#pragma unroll
    for (int nr = 0; nr < 2; ++nr)
#pragma unroll
      for (int h = 0; h < 2; ++h) {
        const int rowb = wc * 32 + nr * 16 + l15;
        const int chb = (k0 >> 3) + h * 4 + lhi;
        bfr[nr][h] = *reinterpret_cast<const short8v*>(&Bs[rowb][(chb ^ (rowb & 7)) * 8]);
      }
#pragma unroll
    for (int mr = 0; mr < 4; ++mr) {
#pragma unroll
      for (int h = 0; h < 2; ++h) {
        const int rowa = wr * 64 + mr * 16 + l15;
        const int cha = (h * 4 + lhi) ^ (rowa & 7);
        const short8v af = *reinterpret_cast<const short8v*>(&As[rowa][cha * 8]);
#pragma unroll
        for (int nr = 0; nr < 2; ++nr)
          acc[mr][nr] = __builtin_amdgcn_mfma_f32_16x16x32_bf16(
              af, bfr[nr][h], acc[mr][nr], 0, 0, 0);
      }
    }
  }
  // ---- epilogue: unguarded stores (pads zero+harmless); stats guarded to real rows ----
  float bcol[2] = {0.f, 0.f};
  if constexpr (MODE == 1) {
#pragma unroll
    for (int nr = 0; nr < 2; ++nr) bcol[nr] = bias[col0 + wc * 32 + nr * 16 + l15];
  }
  float s_c[2] = {0.f, 0.f}, q_c[2] = {0.f, 0.f};
#pragma unroll
  for (int mr = 0; mr < 4; ++mr) {
#pragma unroll
    for (int r = 0; r < 4; ++r) {
      const int grow = row0 + wr * 64 + mr * 16 + lhi * 4 + r;
#pragma unroll
      for (int nr = 0; nr < 2; ++nr) {
        const int gcol = col0 + wc * 32 + nr * 16 + l15;
        const float v = acc[mr][nr][r] + bcol[nr];
        Yb[(size_t)grow * M + gcol] = f2bf(v);
        if constexpr (MODE == 1) {
          if (grow < N_NODES) {
            s_c[nr] += v;
            q_c[nr] += v * v;
          }
        }
      }
    }
  }
  if constexpr (MODE == 1) {
#pragma unroll
    for (int nr = 0; nr < 2; ++nr) {
      float s = s_c[nr], q = q_c[nr];
      s += __shfl_xor(s, 16, 64); q += __shfl_xor(q, 16, 64);
      s += __shfl_xor(s, 32, 64); q += __shfl_xor(q, 32, 64);
      if (lhi == 0) {
        const int cl = wc * 32 + nr * 16 + l15;
        sred[0][cl][wr] = s;
        sred[1][cl][wr] = q;
      }
    }
    __syncthreads();
    if (tid < 128) {
      const int which = tid >> 6;
      const int cl = tid & 63;
      const float tot = sred[which][cl][0] + sred[which][cl][1];
      float* dstp = which ? colsumsq : colsum;
      atomicAdd(&dstp[col0 + cl], tot);
    }
  }
}

// ---------------- pure gather aggregation (half-wave, 16B/lane); zeroes pad rows ----------------
template <int DO, bool ADD_BIAS, bool HAS_RES, bool OUT_BF16>
__global__ __launch_bounds__(256) void aggregate4_kernel(
    const unsigned short* __restrict__ Y, const int* __restrict__ segoff,
    const int* __restrict__ esorted, const float* __restrict__ nisq,
    const float* __restrict__ bias, const float* __restrict__ resid,
    void* __restrict__ Tv) {
  constexpr int V2 = DO / 32;  // bf16 elems per lane per row (128: 4, 256: 8)
  const int wave = threadIdx.x >> 6;
  const int lane = threadIdx.x & 63;
  const int half = lane >> 5;
  const int l31 = lane & 31;
  const int n = blockIdx.x * 4 + wave;
  const int colbase = l31 * V2;
  if (n >= N_NODES) {  // pad row: write zeros so GEMM can load unguarded
    if (half == 0) {
      if constexpr (OUT_BF16) {
        unsigned short* tr = (unsigned short*)Tv + (size_t)n * DO + colbase;
        if constexpr (V2 == 8) *reinterpret_cast<uint4*>(tr) = (uint4){0, 0, 0, 0};
        else *reinterpret_cast<uint2*>(tr) = (uint2){0, 0};
      } else {
        float* tr = (float*)Tv + (size_t)n * DO + colbase;
        if constexpr (V2 == 8) {
          *reinterpret_cast<float4*>(tr) = (float4){0.f, 0.f, 0.f, 0.f};
          *reinterpret_cast<float4*>(tr + 4) = (float4){0.f, 0.f, 0.f, 0.f};
        } else {
          *reinterpret_cast<float4*>(tr) = (float4){0.f, 0.f, 0.f, 0.f};
        }
      }
    }
    return;
  }
  const unsigned short* Yc = Y + colbase;
  float a0[V2], a1[V2];
#pragma unroll
  for (int i = 0; i < V2; ++i) { a0[i] = 0.f; a1[i] = 0.f; }
  const int s = segoff[n];
  const int e = segoff[n + 1];

  if constexpr (V2 == 8) {
    auto acc8 = [&](float* a, const uint4 v) {
      a[0] += bflo(v.x); a[1] += bfhi(v.x);
      a[2] += bflo(v.y); a[3] += bfhi(v.y);
      a[4] += bflo(v.z); a[5] += bfhi(v.z);
      a[6] += bflo(v.w); a[7] += bfhi(v.w);
    };
    int j = s + half;
    for (; j + 2 < e; j += 4) {
      const int i0 = esorted[j];
      const int i1 = esorted[j + 2];
      const uint4 v0 = *reinterpret_cast<const uint4*>(Yc + (size_t)i0 * DO);
      const uint4 v1 = *reinterpret_cast<const uint4*>(Yc + (size_t)i1 * DO);
      acc8(a0, v0); acc8(a1, v1);
    }
    if (j < e) acc8(a0, *reinterpret_cast<const uint4*>(Yc + (size_t)esorted[j] * DO));
    if (half == 0) acc8(a1, *reinterpret_cast<const uint4*>(Yc + (size_t)n * DO));
  } else {
    auto acc4 = [&](float* a, const uint2 v) {
      a[0] += bflo(v.x); a[1] += bfhi(v.x);
      a[2] += bflo(v.y); a[3] += bfhi(v.y);
    };
    int j = s + half;
    for (; j + 2 < e; j += 4) {
      const int i0 = esorted[j];
      const int i1 = esorted[j + 2];
      const uint2 v0 = *reinterpret_cast<const uint2*>(Yc + (size_t)i0 * DO);
      const uint2 v1 = *reinterpret_cast<const uint2*>(Yc + (size_t)i1 * DO);
      acc4(a0, v0); acc4(a1, v1);
    }
    if (j < e) acc4(a0, *reinterpret_cast<const uint2*>(Yc + (size_t)esorted[j] * DO));
    if (half == 0) acc4(a1, *reinterpret_cast<const uint2*>(Yc + (size_t)n * DO));
  }

  const float sc = nisq[n];
  float vals[V2];
#pragma unroll
  for (int i = 0; i < V2; ++i) {
    float t = a0[i] + a1[i];
    t += __shfl_xor(t, 32, 64);
    t *= sc;
    if (half == 0) {
      if (ADD_BIAS) t += bias[colbase + i];
      if (HAS_RES) t += resid[(size_t)n * DO + colbase + i];
    }
    vals[i] = t;
  }
  if (half == 0) {
    if constexpr (OUT_BF16) {
      unsigned short* tr = (unsigned short*)Tv + (size_t)n * DO + colbase;
      if constexpr (V2 == 8) {
        uint4 o;
        o.x = packbf(vals[0], vals[1]); o.y = packbf(vals[2], vals[3]);
        o.z = packbf(vals[4], vals[5]); o.w = packbf(vals[6], vals[7]);
        *reinterpret_cast<uint4*>(tr) = o;
      } else {
        uint2 o;
        o.x = packbf(vals[0], vals[1]); o.y = packbf(vals[2], vals[3]);
        *reinterpret_cast<uint2*>(tr) = o;
      }
    } else {
      float* tr = (float*)Tv + (size_t)n * DO + colbase;
      if constexpr (V2 == 8) {
        float4 o0 = {vals[0], vals[1], vals[2], vals[3]};
        float4 o1 = {vals[4], vals[5], vals[6], vals[7]};
        *reinterpret_cast<float4*>(tr) = o0;
        *reinterpret_cast<float4*>(tr + 4) = o1;
      } else {
        float4 o = {vals[0], vals[1], vals[2], vals[3]};
        *reinterpret_cast<float4*>(tr) = o;
      }
    }
  }
}

// ---------------- column sums for BN stats (bf16 input, L4 only) ----------------
__global__ void stats_bf16_kernel(const unsigned short* __restrict__ T,
                                  float* __restrict__ colsum, float* __restrict__ colsumsq,
                                  int n, int rowsPerBlock) {
  const int t = threadIdx.x;   // 128 threads; thread handles 2 cols (one uint) over half rows
  const int c2 = t & 63;
  const int rh = t >> 6;
  const int r0 = blockIdx.x * rowsPerBlock;
  int r1 = r0 + rowsPerBlock;
  if (r1 > n) r1 = n;
  const unsigned* T32 = (const unsigned*)T;
  float s0 = 0.f, q0 = 0.f, s1 = 0.f, q1 = 0.f;
  for (int r = r0 + rh; r < r1; r += 2) {
    const unsigned v = T32[(size_t)r * 64 + c2];
    const float a = bflo(v), b = bfhi(v);
    s0 += a; q0 += a * a;
    s1 += b; q1 += b * b;
  }
  atomicAdd(&colsum[c2 * 2], s0);
  atomicAdd(&colsumsq[c2 * 2], q0);
  atomicAdd(&colsum[c2 * 2 + 1], s1);
  atomicAdd(&colsumsq[c2 * 2 + 1], q1);
}

// ---------------- BN apply + LeakyReLU + nisq row-scale, bf16 -> bf16 (DO=256); zero pads ----
__global__ void bn_lrelu_nisq_kernel(const unsigned short* __restrict__ Tb,
                                     const float* __restrict__ colsum,
                                     const float* __restrict__ colsumsq,
                                     const float* __restrict__ g, const float* __restrict__ be,
                                     const float* __restrict__ nisq,
                                     unsigned short* __restrict__ outb,
                                     size_t total8, float invN) {
  const size_t idx = (size_t)blockIdx.x * 256 + threadIdx.x;
  if (idx >= total8) return;
  const int row = (int)(idx >> 5);
  if (row >= N_NODES) {  // pad row: table must stay zero for next GEMM
    *reinterpret_cast<uint4*>(&outb[idx * 8]) = (uint4){0, 0, 0, 0};
    return;
  }
  const unsigned c = ((unsigned)idx & 31u) * 8;
  const float sc = nisq[row];
  uint4 v = *reinterpret_cast<const uint4*>(&Tb[idx * 8]);
  float z[8] = {bflo(v.x), bfhi(v.x), bflo(v.y), bfhi(v.y),
                bflo(v.z), bfhi(v.z), bflo(v.w), bfhi(v.w)};
  const float4 cs0 = *reinterpret_cast<const float4*>(&colsum[c]);
  const float4 cs1 = *reinterpret_cast<const float4*>(&colsum[c + 4]);
  const float4 cq0 = *reinterpret_cast<const float4*>(&colsumsq[c]);
  const float4 cq1 = *reinterpret_cast<const float4*>(&colsumsq[c + 4]);
  const float4 gv0 = *reinterpret_cast<const float4*>(&g[c]);
  const float4 gv1 = *reinterpret_cast<const float4*>(&g[c + 4]);
  const float4 bv0 = *reinterpret_cast<const float4*>(&be[c]);
  const float4 bv1 = *reinterpret_cast<const float4*>(&be[c + 4]);
  const float css[8] = {cs0.x, cs0.y, cs0.z, cs0.w, cs1.x, cs1.y, cs1.z, cs1.w};
  const float cqq[8] = {cq0.x, cq0.y, cq0.z, cq0.w, cq1.x, cq1.y, cq1.z, cq1.w};
  const float ggg[8] = {gv0.x, gv0.y, gv0.z, gv0.w, gv1.x, gv1.y, gv1.z, gv1.w};
  const float bbb[8] = {bv0.x, bv0.y, bv0.z, bv0.w, bv1.x, bv1.y, bv1.z, bv1.w};
#pragma unroll
  for (int k = 0; k < 8; ++k) {
    const float m = css[k] * invN;
    const float rs = rsqrtf(cqq[k] * invN - m * m + EPS_C);
    float zz = (z[k] - m) * rs * ggg[k] + bbb[k];
    zz = (zz >= 0.f) ? zz : SLOPE_C * zz;
    z[k] = zz * sc;
  }
  v.x = packbf(z[0], z[1]); v.y = packbf(z[2], z[3]);
  v.z = packbf(z[4], z[5]); v.w = packbf(z[6], z[7]);
  *reinterpret_cast<uint4*>(&outb[idx * 8]) = v;
}

// ---------------- final: BN apply + LayerNorm fused (DO=128, bf16 input) ----------------
__global__ __launch_bounds__(256) void bn_ln_kernel(
    const unsigned short* __restrict__ T, const float* __restrict__ colsum,
    const float* __restrict__ colsumsq, const float* __restrict__ g,
    const float* __restrict__ be, const float* __restrict__ lng,
    const float* __restrict__ lnb, float* __restrict__ out, float invN) {
  const int wave = threadIdx.x >> 6;
  const int lane = threadIdx.x & 63;
  const int n = blockIdx.x * 4 + wave;
  if (n >= N_NODES) return;
  const int c = lane * 2;
  const unsigned tv = *reinterpret_cast<const unsigned*>(&T[(size_t)n * 128 + c]);
  const float t0 = bflo(tv), t1 = bfhi(tv);
  float z[2];
#pragma unroll
  for (int k = 0; k < 2; ++k) {
    const float m = colsum[c + k] * invN;
    const float v = colsumsq[c + k] * invN - m * m;
    const float tvv = (k == 0) ? t0 : t1;
    z[k] = (tvv - m) * rsqrtf(v + EPS_C) * g[c + k] + be[c + k];
  }
  float s = z[0] + z[1];
  float q = z[0] * z[0] + z[1] * z[1];
  for (int o = 32; o > 0; o >>= 1) {
    s += __shfl_xor(s, o, 64);
    q += __shfl_xor(q, o, 64);
  }
  const float mean = s * (1.f / 128.f);
  const float var = q * (1.f / 128.f) - mean * mean;
  const float rs = rsqrtf(var + EPS_C);
  float2 o2;
  o2.x = (z[0] - mean) * rs * lng[c] + lnb[c];
  o2.y = (z[1] - mean) * rs * lng[c + 1] + lnb[c + 1];
  *reinterpret_cast<float2*>(&out[(size_t)n * 128 + c]) = o2;
}

extern "C" void kernel_launch(void* const* d_in, const int* in_sizes, int n_in,
                              void* d_out, int out_size, void* d_ws, size_t ws_size,
                              hipStream_t stream) {
  const float* x = (const float*)d_in[0];
  const int* ei = (const int*)d_in[1];
  const int* srcp = ei;
  const int* dstp = ei + N_EDGES;
  const float* W1 = (const float*)d_in[2];
  const float* b1 = (const float*)d_in[3];
  const float* g1 = (const float*)d_in[4];
  const float* be1 = (const float*)d_in[5];
  const float* W2 = (const float*)d_in[6];
  const float* b2 = (const float*)d_in[7];
  const float* g2 = (const float*)d_in[8];
  const float* be2 = (const float*)d_in[9];
  const float* W3 = (const float*)d_in[10];
  const float* b3 = (const float*)d_in[11];
  const float* g3 = (const float*)d_in[12];
  const float* be3 = (const float*)d_in[13];
  const float* W4 = (const float*)d_in[14];
  const float* b4 = (const float*)d_in[15];
  const float* g4 = (const float*)d_in[16];
  const float* be4 = (const float*)d_in[17];
  const float* lng = (const float*)d_in[18];
  const float* lnb = (const float*)d_in[19];
  float* out = (float*)d_out;

  char* ws = (char*)d_ws;
  size_t off_b = 0;
  auto alloc = [&](size_t bytes) -> void* {
    void* p = (void*)(ws + off_b);
    off_b += (bytes + 255) & ~(size_t)255;
    return p;
  };
  // ---- zero-region (one memset): hist + per-layer stats buffers ----
  int* hist = (int*)alloc((size_t)N_NODES * 4);
  float* cs1 = (float*)alloc(256 * 4);
  float* cq1 = (float*)alloc(256 * 4);
  float* cs2 = (float*)alloc(256 * 4);
  float* cq2 = (float*)alloc(256 * 4);
  float* cs3 = (float*)alloc(256 * 4);
  float* cq3 = (float*)alloc(256 * 4);
  float* cs4 = (float*)alloc(256 * 4);
  float* cq4 = (float*)alloc(256 * 4);
  const size_t zero_bytes = off_b;
  // ---- rest ----
  int* segoff = (int*)alloc((size_t)(N_NODES + 1) * 4);
  int* cursor = (int*)alloc((size_t)N_NODES * 4);
  float* nisq = (float*)alloc((size_t)N_NODES * 4);
  int* esorted = (int*)alloc((size_t)N_EDGES * 4);
  int* partial = (int*)alloc(64 * 4);
  unsigned short* Wt1 = (unsigned short*)alloc((size_t)256 * 128 * 2);
  unsigned short* Wt2 = (unsigned short*)alloc((size_t)256 * 256 * 2);
  unsigned short* Wt3 = (unsigned short*)alloc((size_t)256 * 256 * 2);
  unsigned short* Wt4 = (unsigned short*)alloc((size_t)128 * 256 * 2);
  unsigned short* tblA = (unsigned short*)alloc((size_t)NPAD * 256 * 2);
  unsigned short* tblB = (unsigned short*)alloc((size_t)NPAD * 256 * 2);
  unsigned short* S = (unsigned short*)alloc((size_t)NPAD * 256 * 2);
  unsigned short* Tb = (unsigned short*)alloc((size_t)NPAD * 256 * 2);

  const float invN = 1.0f / (float)N_NODES;
  const int egrid = (N_EDGES + 255) / 256;      // 3125
  const int aggrid = NPAD / 4;                  // covers pad rows (zero-writers)
  const int statgrid = (N_NODES + 127) / 128;
  const int mgrid256 = (NPAD / 128) * 4;        // 1568 (= 0 mod 8)
  const int mgrid128 = (NPAD / 128) * 2;        // 784  (= 0 mod 8)
  const unsigned bngrid = (unsigned)(((size_t)NPAD * 32 + 255) / 256);

  // ---- zero hist + all stats buffers in ONE memset ----
  hipMemsetAsync(hist, 0, zero_bytes, stream);

  // ---- fused: degrees + weight transpose/cast ----
  hist_wcast_kernel<<<HGRID + 768, 256, 0, stream>>>(dstp, hist, W1, W2, W3, W4,
                                                     Wt1, Wt2, Wt3, Wt4);
  scan1_kernel<<<NBCH, 1024, 0, stream>>>(hist, segoff, partial, nisq, N_NODES);
  // ---- fused: scan finalize + scale_cast (tblA = bf16(x*nisq)) ----
  scan3f_kernel<<<SGRID + 6250, 256, 0, stream>>>(segoff, cursor, partial, nisq, x, tblA);
  scatter_kernel<<<egrid, 256, 0, stream>>>(srcp, dstp, cursor, esorted, N_EDGES);

  // ---- Layer 1: S = A_hat-gather(tblA); Tb = S W1 + b1 (+stats); bn*nisq -> tblB ----
  aggregate4_kernel<128, false, false, true><<<aggrid, 256, 0, stream>>>(
      tblA, segoff, esorted, nisq, nullptr, nullptr, S);
  gemm2_kernel<1, 128, 2><<<mgrid256, 256, 0, stream>>>(S, Wt1, b1, Tb, cs1, cq1, 256);
  bn_lrelu_nisq_kernel<<<bngrid, 256, 0, stream>>>(Tb, cs1, cq1, g1, be1, nisq,
                                                   tblB, (size_t)NPAD * 32, invN);

  // ---- Layer 2 ----
  aggregate4_kernel<256, false, false, true><<<aggrid, 256, 0, stream>>>(
      tblB, segoff, esorted, nisq, nullptr, nullptr, S);
  gemm2_kernel<1, 256, 2><<<mgrid256, 256, 0, stream>>>(S, Wt2, b2, Tb, cs2, cq2, 256);
  bn_lrelu_nisq_kernel<<<bngrid, 256, 0, stream>>>(Tb, cs2, cq2, g2, be2, nisq,
                                                   tblA, (size_t)NPAD * 32, invN);

  // ---- Layer 3 ----
  aggregate4_kernel<256, false, false, true><<<aggrid, 256, 0, stream>>>(
      tblA, segoff, esorted, nisq, nullptr, nullptr, S);
  gemm2_kernel<1, 256, 2><<<mgrid256, 256, 0, stream>>>(S, Wt3, b3, Tb, cs3, cq3, 256);
  bn_lrelu_nisq_kernel<<<bngrid, 256, 0, stream>>>(Tb, cs3, cq3, g3, be3, nisq,
                                                   tblB, (size_t)NPAD * 32, invN);

  // ---- Layer 4: S = tblB·W4 (nisq pre-folded); agg(+b4+resid) -> bf16; stats; BN+LN ----
  gemm2_kernel<0, 256, 1><<<mgrid128, 256, 0, stream>>>(tblB, Wt4, nullptr, S,
                                                        nullptr, nullptr, 128);
  aggregate4_kernel<128, true, true, true><<<aggrid, 256, 0, stream>>>(
      S, segoff, esorted, nisq, b4, x, Tb);
  stats_bf16_kernel<<<statgrid, 128, 0, stream>>>(Tb, cs4, cq4, N_NODES, 128);
  bn_ln_kernel<<<(N_NODES + 3) / 4, 256, 0, stream>>>(Tb, cs4, cq4, g4, be4, lng, lnb, out, invN);
}